// Round 20
// baseline (204.628 us; speedup 1.0000x reference)
//
#include <hip/hip_runtime.h>
#include <hip/hip_bf16.h>
#include <math.h>

// EpisodicMemory round 20: r19 + ONE change — pre2 qgemm branch reads B
// (Wq_bf, L2-resident 512KB) DIRECTLY into MFMA fragment registers instead of
// LDS-staging it. Swizzle algebra cancels: value read is always global chunk
// lhi -> bit-identical math. LDS arena 68.5KB -> 8KB; occupancy becomes
// VGPR-bound (~12 waves/CU vs ~8), bank conflicts removed.
// ws layout unchanged.

#define B_ 16384
#define D_ 512
#define E_ 1024

typedef __attribute__((ext_vector_type(8))) short bf16x8;
typedef __attribute__((ext_vector_type(4))) float f32x4;
typedef __attribute__((ext_vector_type(8))) unsigned short u16x8;

__device__ __forceinline__ unsigned short f2bf(float f) {
  unsigned u = __builtin_bit_cast(unsigned, f);
  unsigned r = (u + 0x7fffu + ((u >> 16) & 1u)) >> 16;
  return (unsigned short)r;
}
__device__ __forceinline__ float bf2f(unsigned short u) {
  return __builtin_bit_cast(float, (unsigned)u << 16);
}

#define GLDS16(g, l)                                                          \
  __builtin_amdgcn_global_load_lds(                                           \
      (const __attribute__((address_space(1))) void*)(g),                     \
      (__attribute__((address_space(3))) void*)(l), 16, 0, 0)

// ---------- prep: blocks 0..255 l2norm_keys; 256..511 transpose; 512.. cvt4 --
__global__ __launch_bounds__(256) void prep(
    const float* __restrict__ keys, float* __restrict__ keysN,
    unsigned short* __restrict__ kn_bf,
    const float* __restrict__ Wq, float* __restrict__ WqT,
    const float* __restrict__ Wv, const float* __restrict__ Wg,
    const float* __restrict__ vals,
    unsigned short* __restrict__ Wq_bf, unsigned short* __restrict__ Wv_bf,
    unsigned short* __restrict__ Wg_bf, unsigned short* __restrict__ vals_bf) {
  const int blk = blockIdx.x;
  if (blk < 256) {
    const int row  = blk * 4 + (threadIdx.x >> 6);
    const int lane = threadIdx.x & 63;
    const float4* p4 = (const float4*)(keys + (size_t)row * D_);
    float4 a = p4[lane];
    float4 b = p4[lane + 64];
    float ss = a.x*a.x + a.y*a.y + a.z*a.z + a.w*a.w
             + b.x*b.x + b.y*b.y + b.z*b.z + b.w*b.w;
#pragma unroll
    for (int off = 32; off > 0; off >>= 1) ss += __shfl_xor(ss, off, 64);
    const float inv = 1.0f / fmaxf(sqrtf(ss), 1e-12f);
    a.x *= inv; a.y *= inv; a.z *= inv; a.w *= inv;
    b.x *= inv; b.y *= inv; b.z *= inv; b.w *= inv;
    float4* o4 = (float4*)(keysN + (size_t)row * D_);
    o4[lane]      = a;
    o4[lane + 64] = b;
    ushort4 ua, ub;
    ua.x=f2bf(a.x); ua.y=f2bf(a.y); ua.z=f2bf(a.z); ua.w=f2bf(a.w);
    ub.x=f2bf(b.x); ub.y=f2bf(b.y); ub.z=f2bf(b.z); ub.w=f2bf(b.w);
    *(ushort4*)(kn_bf + (size_t)row * D_ + 4*lane)       = ua;
    *(ushort4*)(kn_bf + (size_t)row * D_ + 256 + 4*lane) = ub;
  } else if (blk < 512) {
    __shared__ float t[32][33];
    const int g = blk - 256;
    const int bx = g & 15, by = g >> 4;
    const int tx = threadIdx.x & 31, ty = threadIdx.x >> 5;
#pragma unroll
    for (int k = 0; k < 4; k++)
      t[ty + 8*k][tx] = Wq[(size_t)(by*32 + ty + 8*k) * 512 + bx*32 + tx];
    __syncthreads();
#pragma unroll
    for (int k = 0; k < 4; k++)
      WqT[(size_t)(bx*32 + ty + 8*k) * 512 + by*32 + tx] = t[tx][ty + 8*k];
  } else {
    const int cb = blk - 512;
    const float* in;
    unsigned short* out;
    int i;
    if (cb < 128)      { in = Wq;   out = Wq_bf;   i = cb * 256 + threadIdx.x; }
    else if (cb < 256) { in = Wv;   out = Wv_bf;   i = (cb - 128) * 256 + threadIdx.x; }
    else if (cb < 512) { in = Wg;   out = Wg_bf;   i = (cb - 256) * 256 + threadIdx.x; }
    else               { in = vals; out = vals_bf; i = (cb - 512) * 256 + threadIdx.x; }
    const float4 a = ((const float4*)in)[2*i];
    const float4 b = ((const float4*)in)[2*i+1];
    u16x8 o;
    o[0]=f2bf(a.x); o[1]=f2bf(a.y); o[2]=f2bf(a.z); o[3]=f2bf(a.w);
    o[4]=f2bf(b.x); o[5]=f2bf(b.y); o[6]=f2bf(b.z); o[7]=f2bf(b.w);
    *(u16x8*)(out + 8*i) = o;
  }
}

// ---------- pre2: blocks 0..127 = sgemm64 (Kp); 128..639 = qgemm (32 rows) ---
// qgemm: A staged in LDS (4KB dbuf, shared by waves); B read DIRECTLY from
// L2-resident Wq_bf into fragment registers (global chunk lhi — swizzle
// cancels). Arena = 8KB (sgemm needs 8KB; qgemm 4.6KB).
__global__ __launch_bounds__(256) void pre2(
    const float* __restrict__ A, const float* __restrict__ Bm,
    float* __restrict__ C,
    const float* __restrict__ query, const unsigned short* __restrict__ Wqbf,
    unsigned short* __restrict__ qnbf, unsigned short* __restrict__ qbf,
    float* __restrict__ invq) {
  __shared__ __align__(16) char arena[8704];
  const int tid = threadIdx.x;

  if (blockIdx.x < 128) {
    // ================= sgemm64 branch (verbatim) =================
    float (*As)[64] = (float(*)[64])(arena);
    float (*Bs)[64] = (float(*)[64])(arena + 4096);
    const int g = blockIdx.x;
    const int bn = g & 7, bm = g >> 3;
    const int tm = tid >> 4, tn = tid & 15;
    const int r = tid >> 2, k4 = (tid & 3) * 4;
    const float* Ap = A  + (size_t)(bm*64 + r) * 512 + k4;
    const float* Bp = Bm + (size_t)(bn*64 + r) * 512 + k4;
    float acc[4][4];
#pragma unroll
    for (int i = 0; i < 4; i++)
#pragma unroll
      for (int j = 0; j < 4; j++) acc[i][j] = 0.0f;

    for (int k0 = 0; k0 < 512; k0 += 16) {
      const float4 av = *(const float4*)(Ap + k0);
      const float4 bv = *(const float4*)(Bp + k0);
      As[k4+0][r]=av.x; As[k4+1][r]=av.y; As[k4+2][r]=av.z; As[k4+3][r]=av.w;
      Bs[k4+0][r]=bv.x; Bs[k4+1][r]=bv.y; Bs[k4+2][r]=bv.z; Bs[k4+3][r]=bv.w;
      __syncthreads();
#pragma unroll
      for (int k = 0; k < 16; k++) {
        const float4 a = *(const float4*)&As[k][tm*4];
        const float4 b = *(const float4*)&Bs[k][tn*4];
        const float aa[4] = {a.x,a.y,a.z,a.w}, bb[4] = {b.x,b.y,b.z,b.w};
#pragma unroll
        for (int i = 0; i < 4; i++)
#pragma unroll
          for (int j = 0; j < 4; j++) acc[i][j] = fmaf(aa[i], bb[j], acc[i][j]);
      }
      __syncthreads();
    }
#pragma unroll
    for (int i = 0; i < 4; i++) {
      float4 o = make_float4(acc[i][0], acc[i][1], acc[i][2], acc[i][3]);
      *(float4*)(C + (size_t)(bm*64 + tm*4 + i) * 512 + bn*64 + tn*4) = o;
    }
    return;
  }

  // ============ qgemm branch: 32 rows/block, B direct from global ============
  unsigned short* AsB = (unsigned short*)(arena);            // [2][32*32] = 4KB
  float (*rowss)[32] = (float(*)[32])(arena + 4096);         // [4][32]
  const int wv = tid >> 6, l = tid & 63;
  const int m0 = (blockIdx.x - 128) * 32;
  const int lane16 = l & 15, lhi = l >> 4;

  f32x4 acc[2][8];
#pragma unroll
  for (int mi = 0; mi < 2; mi++)
#pragma unroll
    for (int nj = 0; nj < 8; nj++)
#pragma unroll
      for (int r = 0; r < 4; r++) acc[mi][nj][r] = 0.0f;

  auto stage = [&](int buf, int t) {
    const int k0 = t * 32;
    if (tid < 128) {  // A: 32 rows x 4 chunks = 128 chunks (swizzled, as before)
      const int p = tid;
      const int r = p >> 2, c = p & 3;
      const int q = k0 + 8 * (c ^ ((r >> 1) & 3));
      const float* src = query + (size_t)(m0 + r) * 512 + q;
      const float4 f0 = *(const float4*)src;
      const float4 f1 = *(const float4*)(src + 4);
      u16x8 o;
      o[0]=f2bf(f0.x); o[1]=f2bf(f0.y); o[2]=f2bf(f0.z); o[3]=f2bf(f0.w);
      o[4]=f2bf(f1.x); o[5]=f2bf(f1.y); o[6]=f2bf(f1.z); o[7]=f2bf(f1.w);
      *(u16x8*)&AsB[buf * 1024 + p * 8] = o;
      *(u16x8*)(qbf + (size_t)(m0 + r) * 512 + q) = o;
    }
  };
  auto compute = [&](int buf, int t) {
    const int k0 = t * 32;
    const int achunk = lhi ^ ((lane16 >> 1) & 3);
    bf16x8 af[2], bfr[8];
#pragma unroll
    for (int mi = 0; mi < 2; ++mi)
      af[mi] = *(const bf16x8*)&AsB[buf * 1024 + (mi * 16 + lane16) * 32 + achunk * 8];
#pragma unroll
    for (int nj = 0; nj < 8; ++nj)   // B direct: global chunk lhi (L2-resident)
      bfr[nj] = *(const bf16x8*)&Wqbf[(size_t)(wv * 128 + nj * 16 + lane16) * 512 + k0 + lhi * 8];
#pragma unroll
    for (int mi = 0; mi < 2; ++mi)
#pragma unroll
      for (int nj = 0; nj < 8; ++nj)
        acc[mi][nj] = __builtin_amdgcn_mfma_f32_16x16x32_bf16(af[mi], bfr[nj], acc[mi][nj], 0, 0, 0);
  };

  stage(0, 0);
  __syncthreads();
  for (int t = 0; t < 15; ++t) {
    stage((t + 1) & 1, t + 1);
    compute(t & 1, t);
    __syncthreads();
  }
  compute(1, 15);

  float ss[2][4];
#pragma unroll
  for (int mi = 0; mi < 2; mi++)
#pragma unroll
    for (int r = 0; r < 4; r++) ss[mi][r] = 0.0f;
#pragma unroll
  for (int mi = 0; mi < 2; mi++)
#pragma unroll
    for (int nj = 0; nj < 8; nj++)
#pragma unroll
      for (int r = 0; r < 4; r++) {
        const float x = acc[mi][nj][r];
        ss[mi][r] = fmaf(x, x, ss[mi][r]);
      }
#pragma unroll
  for (int off = 1; off < 16; off <<= 1)
#pragma unroll
    for (int mi = 0; mi < 2; mi++)
#pragma unroll
      for (int r = 0; r < 4; r++) ss[mi][r] += __shfl_xor(ss[mi][r], off, 64);
  if (lane16 == 0) {
#pragma unroll
    for (int mi = 0; mi < 2; mi++)
#pragma unroll
      for (int r = 0; r < 4; r++) rowss[wv][mi * 16 + lhi * 4 + r] = ss[mi][r];
  }
  __syncthreads();

#pragma unroll
  for (int mi = 0; mi < 2; mi++) {
#pragma unroll
    for (int r = 0; r < 4; r++) {
      const int row = mi * 16 + lhi * 4 + r;
      const float tot = rowss[0][row] + rowss[1][row] + rowss[2][row] + rowss[3][row];
      const float inv = 1.0f / fmaxf(sqrtf(tot), 1e-12f);
      if (wv == 0 && lane16 == 0) invq[m0 + row] = inv;
#pragma unroll
      for (int nj = 0; nj < 8; nj++)
        qnbf[(size_t)(m0 + row) * 512 + wv * 128 + nj * 16 + lane16] =
            f2bf(acc[mi][nj][r] * inv);
    }
  }
}

// ---------- bf16 MFMA NT GEMM, 128x128, bm-fast ------------------------------
// MODE 0 (sim/wv): A=A0bf;        out: bf16 outbf
// MODE 2 (gate):   A=[A0bf | A1]; out: sigmoid(acc+bg)*bf2f(projbf) -> outf (NT)
template<int KTOT, int NOUT, int MODE>
__global__ __launch_bounds__(256) void mfma_nt(
    const unsigned short* __restrict__ A0bf,
    const unsigned short* __restrict__ A1,
    const unsigned short* __restrict__ Bw,
    const float* __restrict__ bg,
    const unsigned short* __restrict__ projbf,
    float* __restrict__ outf,
    unsigned short* __restrict__ outbf) {
  __shared__ __align__(16) unsigned short As[2][128 * 32];
  __shared__ __align__(16) unsigned short Bs[2][128 * 32];
  const int tid = threadIdx.x;
  const int wv = tid >> 6, l = tid & 63;
  const int bm = blockIdx.x, bn = blockIdx.y;   // bm fast -> XCD shares A
  const int wr = wv >> 1, wc = wv & 1;
  const int lane16 = l & 15, lhi = l >> 4;

  f32x4 acc[4][4];
#pragma unroll
  for (int mi = 0; mi < 4; mi++)
#pragma unroll
    for (int nj = 0; nj < 4; nj++)
#pragma unroll
      for (int r = 0; r < 4; r++) acc[mi][nj][r] = 0.0f;

  auto stage = [&](int buf, int t) {
    const int k0 = t * 32;
#pragma unroll
    for (int h = 0; h < 2; ++h) {
      const int p = tid + 256 * h;
      const int r = p >> 2, c = p & 3;
      const int q = k0 + 8 * (c ^ ((r >> 1) & 3));
      const unsigned short* asrc;
      if constexpr (MODE == 2) {
        asrc = (q < 512) ? (A0bf + (size_t)(bm * 128 + r) * 512 + q)
                         : (A1   + (size_t)(bm * 128 + r) * 512 + (q - 512));
      } else {
        asrc = A0bf + (size_t)(bm * 128 + r) * 512 + q;
      }
      GLDS16(asrc, &As[buf][(4 * h + wv) * 512]);
      const unsigned short* bsrc = Bw + (size_t)(bn * 128 + r) * KTOT + q;
      GLDS16(bsrc, &Bs[buf][(4 * h + wv) * 512]);
    }
  };

  auto compute = [&](int buf) {
    const int achunk = lhi ^ ((lane16 >> 1) & 3);
    bf16x8 af[4], bfr[4];
#pragma unroll
    for (int mi = 0; mi < 4; ++mi)
      af[mi] = *(const bf16x8*)&As[buf][(wr * 64 + mi * 16 + lane16) * 32 + achunk * 8];
#pragma unroll
    for (int nj = 0; nj < 4; ++nj)
      bfr[nj] = *(const bf16x8*)&Bs[buf][(wc * 64 + nj * 16 + lane16) * 32 + achunk * 8];
#pragma unroll
    for (int mi = 0; mi < 4; ++mi)
#pragma unroll
      for (int nj = 0; nj < 4; ++nj)
        acc[mi][nj] = __builtin_amdgcn_mfma_f32_16x16x32_bf16(af[mi], bfr[nj], acc[mi][nj], 0, 0, 0);
  };

  const int NT = KTOT / 32;
  stage(0, 0);
  __syncthreads();
  for (int t = 0; t < NT - 1; ++t) {
    stage((t + 1) & 1, t + 1);
    compute(t & 1);
    __syncthreads();
  }
  compute((NT - 1) & 1);

  const int rowb = bm * 128 + wr * 64 + (lhi << 2);
  const int colb = bn * 128 + wc * 64 + lane16;
#pragma unroll
  for (int mi = 0; mi < 4; ++mi) {
#pragma unroll
    for (int nj = 0; nj < 4; ++nj) {
      const int col = colb + nj * 16;
#pragma unroll
      for (int r = 0; r < 4; ++r) {
        const int row = rowb + mi * 16 + r;
        const size_t o = (size_t)row * NOUT + col;
        const float v = acc[mi][nj][r];
        if constexpr (MODE == 2) {
          const float x = v + bg[col];
          const float g = 1.0f / (1.0f + __expf(-x));
          __builtin_nontemporal_store(g * bf2f(projbf[o]), &outf[o]);
        } else {
          outbf[o] = f2bf(v);
        }
      }
    }
  }
}

// ---------- topk (r14/r16/r17 EXACT body) ------------------------------------
__global__ __launch_bounds__(256) void topk_rescore_gather(
    const unsigned short* __restrict__ simbf,
    const float* __restrict__ query,
    const float* __restrict__ invq,
    const float* __restrict__ Kp,
    const unsigned short* __restrict__ valsbf,
    unsigned short* __restrict__ retr) {
  const int w = threadIdx.x >> 6, l = threadIdx.x & 63;
  const int b = blockIdx.x * 4 + w;

  const u16x8* sp = (const u16x8*)(simbf + (size_t)b * E_ + 16 * l);
  const u16x8 s0 = sp[0], s1 = sp[1];
  const float4* qp = (const float4*)(query + (size_t)b * D_ + 8 * l);
  const float4 q0 = qp[0], q1 = qp[1];

  float v[16];
  unsigned pk[16];
#pragma unroll
  for (int j = 0; j < 8; j++) {
    const unsigned u0 = (unsigned short)s0[j];
    const unsigned u1 = (unsigned short)s1[j];
    v[j]     = bf2f((unsigned short)u0);
    v[8 + j] = bf2f((unsigned short)u1);
    const unsigned k0 = u0 ^ ((u0 & 0x8000u) ? 0xFFFFu : 0x8000u);
    const unsigned k1 = u1 ^ ((u1 & 0x8000u) ? 0xFFFFu : 0x8000u);
    pk[j]     = (k0 << 16) | (1023u - (unsigned)(l * 16 + j));
    pk[8 + j] = (k1 << 16) | (1023u - (unsigned)(l * 16 + 8 + j));
  }

  unsigned t0 = 0, t1 = 0, t2 = 0, t3 = 0;
#pragma unroll
  for (int j = 0; j < 16; j++) {
    const unsigned x = pk[j];
    const unsigned a = min(t0, x); t0 = max(t0, x);
    const unsigned c = min(t1, a); t1 = max(t1, a);
    const unsigned d = min(t2, c); t2 = max(t2, c);
    t3 = max(t3, d);
  }

#pragma unroll
  for (int off = 1; off < 64; off <<= 1) {
    const unsigned b0 = (unsigned)__shfl_xor((int)t0, off, 64);
    const unsigned b1 = (unsigned)__shfl_xor((int)t1, off, 64);
    const unsigned b2 = (unsigned)__shfl_xor((int)t2, off, 64);
    const unsigned b3 = (unsigned)__shfl_xor((int)t3, off, 64);
    const unsigned c0 = max(t0, b3), c1 = max(t1, b2);
    const unsigned c2 = max(t2, b1), c3 = max(t3, b0);
    const unsigned d0 = max(c0, c2), d2 = min(c0, c2);
    const unsigned d1 = max(c1, c3), d3 = min(c1, c3);
    t0 = max(d0, d1); t1 = min(d0, d1);
    t2 = max(d2, d3); t3 = min(d2, d3);
  }

  const int i0 = 1023 - (int)(t0 & 1023u);
  const int i1 = 1023 - (int)(t1 & 1023u);
  const int i2 = 1023 - (int)(t2 & 1023u);
  const int i3 = 1023 - (int)(t3 & 1023u);
  const unsigned k16 = t3 >> 16;
  const unsigned u4 = (k16 & 0x8000u) ? (k16 ^ 0x8000u) : (~k16 & 0xFFFFu);
  const float thr = bf2f((unsigned short)u4) - 0.008f;

  const float4* kp0 = (const float4*)(Kp + (size_t)i0 * D_ + 8 * l);
  const float4* kp1 = (const float4*)(Kp + (size_t)i1 * D_ + 8 * l);
  const float4* kp2 = (const float4*)(Kp + (size_t)i2 * D_ + 8 * l);
  const float4* kp3 = (const float4*)(Kp + (size_t)i3 * D_ + 8 * l);
  const float4 a0 = kp0[0], c0 = kp0[1];
  const float4 a1 = kp1[0], c1 = kp1[1];
  const float4 a2 = kp2[0], c2 = kp2[1];
  const float4 a3 = kp3[0], c3 = kp3[1];
  float p0 = q0.x*a0.x, p1 = q0.x*a1.x, p2 = q0.x*a2.x, p3 = q0.x*a3.x;
  p0=fmaf(q0.y,a0.y,p0); p1=fmaf(q0.y,a1.y,p1); p2=fmaf(q0.y,a2.y,p2); p3=fmaf(q0.y,a3.y,p3);
  p0=fmaf(q0.z,a0.z,p0); p1=fmaf(q0.z,a1.z,p1); p2=fmaf(q0.z,a2.z,p2); p3=fmaf(q0.z,a3.z,p3);
  p0=fmaf(q0.w,a0.w,p0); p1=fmaf(q0.w,a1.w,p1); p2=fmaf(q0.w,a2.w,p2); p3=fmaf(q0.w,a3.w,p3);
  p0=fmaf(q1.x,c0.x,p0); p1=fmaf(q1.x,c1.x,p1); p2=fmaf(q1.x,c2.x,p2); p3=fmaf(q1.x,c3.x,p3);
  p0=fmaf(q1.y,c0.y,p0); p1=fmaf(q1.y,c1.y,p1); p2=fmaf(q1.y,c2.y,p2); p3=fmaf(q1.y,c3.y,p3);
  p0=fmaf(q1.z,c0.z,p0); p1=fmaf(q1.z,c1.z,p1); p2=fmaf(q1.z,c2.z,p2); p3=fmaf(q1.z,c3.z,p3);
  p0=fmaf(q1.w,c0.w,p0); p1=fmaf(q1.w,c1.w,p1); p2=fmaf(q1.w,c2.w,p2); p3=fmaf(q1.w,c3.w,p3);
#pragma unroll
  for (int off = 32; off > 0; off >>= 1) {
    p0 += __shfl_xor(p0, off, 64);
    p1 += __shfl_xor(p1, off, 64);
    p2 += __shfl_xor(p2, off, 64);
    p3 += __shfl_xor(p3, off, 64);
  }

  const float NEG = -3.402823466e38f;
  float rv0 = NEG, rv1 = NEG, rv2 = NEG, rv3 = NEG;
  int   ri0 = 0x7fffffff, ri1 = 0x7fffffff, ri2 = 0x7fffffff, ri3 = 0x7fffffff;
  auto ins = [&](float nv, int ni) {
    if (nv > rv0 || (nv == rv0 && ni < ri0)) {
      rv3 = rv2; ri3 = ri2; rv2 = rv1; ri2 = ri1; rv1 = rv0; ri1 = ri0; rv0 = nv; ri0 = ni;
    } else if (nv > rv1 || (nv == rv1 && ni < ri1)) {
      rv3 = rv2; ri3 = ri2; rv2 = rv1; ri2 = ri1; rv1 = nv; ri1 = ni;
    } else if (nv > rv2 || (nv == rv2 && ni < ri2)) {
      rv3 = rv2; ri3 = ri2; rv2 = nv; ri2 = ni;
    } else if (nv > rv3 || (nv == rv3 && ni < ri3)) {
      rv3 = nv; ri3 = ni;
    }
  };
  ins(p0, i0); ins(p1, i1); ins(p2, i2); ins(p3, i3);

  auto score = [&](int idx) -> float {
    const float4* kp = (const float4*)(Kp + (size_t)idx * D_ + 8 * l);
    const float4 k0 = kp[0], k1 = kp[1];
    float p = q0.x * k0.x;
    p = fmaf(q0.y, k0.y, p); p = fmaf(q0.z, k0.z, p); p = fmaf(q0.w, k0.w, p);
    p = fmaf(q1.x, k1.x, p); p = fmaf(q1.y, k1.y, p);
    p = fmaf(q1.z, k1.z, p); p = fmaf(q1.w, k1.w, p);
#pragma unroll
    for (int off = 32; off > 0; off >>= 1) p += __shfl_xor(p, off, 64);
    return p;
  };
#pragma unroll
  for (int s = 0; s < 16; s++) {
    const int idx = l * 16 + s;
    const bool pred = (v[s] >= thr) && idx != i0 && idx != i1 && idx != i2 && idx != i3;
    unsigned long long m = __ballot(pred);
    while (m) {
      const int ln = __builtin_ctzll(m);
      m &= m - 1;
      const int ci = ln * 16 + s;
      ins(score(ci), ci);
    }
  }

  const float iq = invq[b];
  const float f0 = rv0 * iq, f1 = rv1 * iq, f2 = rv2 * iq, f3 = rv3 * iq;
  const float mx = 5.0f * f0;
  const float e0 = expf(5.0f * f0 - mx), e1 = expf(5.0f * f1 - mx);
  const float e2 = expf(5.0f * f2 - mx), e3 = expf(5.0f * f3 - mx);
  const float wi = 1.0f / (e0 + e1 + e2 + e3);
  const float w0 = e0 * wi, w1 = e1 * wi, w2 = e2 * wi, w3 = e3 * wi;

  const u16x8 g0 = *(const u16x8*)(valsbf + (size_t)ri0 * D_ + 8 * l);
  const u16x8 g1 = *(const u16x8*)(valsbf + (size_t)ri1 * D_ + 8 * l);
  const u16x8 g2 = *(const u16x8*)(valsbf + (size_t)ri2 * D_ + 8 * l);
  const u16x8 g3 = *(const u16x8*)(valsbf + (size_t)ri3 * D_ + 8 * l);
  u16x8 o;
#pragma unroll
  for (int j = 0; j < 8; j++) {
    o[j] = f2bf(w0 * bf2f((unsigned short)g0[j]) + w1 * bf2f((unsigned short)g1[j]) +
                w2 * bf2f((unsigned short)g2[j]) + w3 * bf2f((unsigned short)g3[j]));
  }
  *(u16x8*)(retr + (size_t)b * D_ + 8 * l) = o;
}

extern "C" void kernel_launch(void* const* d_in, const int* in_sizes, int n_in,
                              void* d_out, int out_size, void* d_ws, size_t ws_size,
                              hipStream_t stream) {
  (void)in_sizes; (void)n_in; (void)out_size; (void)ws_size;
  const float* query = (const float*)d_in[0];
  const float* keys  = (const float*)d_in[1];
  const float* vals  = (const float*)d_in[2];
  const float* Wq    = (const float*)d_in[3];
  const float* Wv    = (const float*)d_in[4];
  const float* Wg    = (const float*)d_in[5];
  const float* bg    = (const float*)d_in[6];
  float* out = (float*)d_out;

  char* ws = (char*)d_ws;
  const size_t M = 1u << 20;
  unsigned short* sim_bf   = (unsigned short*)(ws);          // [0,32M)
  unsigned short* qn_bf    = (unsigned short*)(ws + 32*M);   // [32M,48M)
  unsigned short* retr_bf  = (unsigned short*)(ws + 32*M);   // overlay after sim
  unsigned short* proj_bf  = (unsigned short*)(ws + 48*M);   // [48M,64M)
  float*          keysN    = (float*)(ws + 64*M);            // 2 MB
  unsigned short* kn_bf    = (unsigned short*)(ws + 66*M);   // 1 MB
  float*          WqT      = (float*)(ws + 67*M);            // 1 MB
  float*          Kp       = (float*)(ws + 68*M);            // 2 MB
  unsigned short* Wq_bf    = (unsigned short*)(ws + 70*M);   // 0.5 MB
  unsigned short* Wv_bf    = (unsigned short*)(ws + 70*M + 512*1024u);
  unsigned short* Wg_bf    = (unsigned short*)(ws + 71*M);   // 1 MB
  float*          invq     = (float*)(ws + 72*M);            // 64 KB
  unsigned short* query_bf = (unsigned short*)(ws + 74*M);   // [74M,90M)
  unsigned short* vals_bf  = (unsigned short*)(ws + 90*M);   // 1 MB

  // fused prep: l2norm_keys + WqT transpose + bf16 conversions
  prep<<<1280, 256, 0, stream>>>(keys, keysN, kn_bf, Wq, WqT, Wv, Wg, vals,
                                 Wq_bf, Wv_bf, Wg_bf, vals_bf);

  // fused: Kp GEMM (blocks 0..127) || qgemm 32-row, B-from-L2 (128..639)
  pre2<<<640, 256, 0, stream>>>(keysN, WqT, Kp,
                                query, Wq_bf, qn_bf, query_bf, invq);

  // coarse sim (bf16 out): [B,E]; bm fast
  mfma_nt<512, 1024, 0><<<dim3(B_ / 128, E_ / 128), 256, 0, stream>>>(
      qn_bf, nullptr, kn_bf, nullptr, nullptr, nullptr, sim_bf);

  topk_rescore_gather<<<B_ / 4, 256, 0, stream>>>(sim_bf, query, invq, Kp,
                                                  vals_bf, retr_bf);

  // proj = retrieved @ Wv^T; bm fast
  mfma_nt<512, 512, 0><<<dim3(B_ / 128, D_ / 128), 256, 0, stream>>>(
      retr_bf, nullptr, Wv_bf, nullptr, nullptr, nullptr, proj_bf);

  // out = sigmoid([query|proj] @ Wg^T + bg) * proj; bm fast; NT out store
  mfma_nt<1024, 512, 2><<<dim3(B_ / 128, D_ / 128), 256, 0, stream>>>(
      query_bf, proj_bf, Wg_bf, bg, proj_bf, out, nullptr);
}

// Round 21
// 191.657 us; speedup vs baseline: 1.0677x; 1.0677x over previous
//
#include <hip/hip_runtime.h>
#include <hip/hip_bf16.h>
#include <math.h>

// EpisodicMemory FINAL (r21 = r18 exact revert; best passing config, 192.2us).
// r19/r20 pre2 experiments both regressed (66/75 vs 64us) -> r18 pre2 restored.
// Pipeline: prep (l2norm_keys+transpose+cvt4) -> pre2 (Kp GEMM || qgemm_norm)
// -> sim MFMA -> fused topk (coarse sort + fp32 rescore + gather) -> wv MFMA
// -> gate MFMA (NT out store). absmax 0.0156 vs threshold 0.0413.
// ws layout:
//   [0,32M) sim_bf   [32M,48M) qn_bf -> retr_bf   [48M,64M) proj_bf
//   [64M,66M) keysN  [66M,67M) kn_bf  [67M,68M) WqT  [68M,70M) Kp
//   [70M) Wq_bf [70.5M) Wv_bf [71M) Wg_bf [72M) invq [74M,90M) query_bf
//   [90M,91M) vals_bf

#define B_ 16384
#define D_ 512
#define E_ 1024

typedef __attribute__((ext_vector_type(8))) short bf16x8;
typedef __attribute__((ext_vector_type(4))) float f32x4;
typedef __attribute__((ext_vector_type(8))) unsigned short u16x8;

__device__ __forceinline__ unsigned short f2bf(float f) {
  unsigned u = __builtin_bit_cast(unsigned, f);
  unsigned r = (u + 0x7fffu + ((u >> 16) & 1u)) >> 16;
  return (unsigned short)r;
}
__device__ __forceinline__ float bf2f(unsigned short u) {
  return __builtin_bit_cast(float, (unsigned)u << 16);
}

#define GLDS16(g, l)                                                          \
  __builtin_amdgcn_global_load_lds(                                           \
      (const __attribute__((address_space(1))) void*)(g),                     \
      (__attribute__((address_space(3))) void*)(l), 16, 0, 0)

// ---------- prep: blocks 0..255 l2norm_keys; 256..511 transpose; 512.. cvt4 --
__global__ __launch_bounds__(256) void prep(
    const float* __restrict__ keys, float* __restrict__ keysN,
    unsigned short* __restrict__ kn_bf,
    const float* __restrict__ Wq, float* __restrict__ WqT,
    const float* __restrict__ Wv, const float* __restrict__ Wg,
    const float* __restrict__ vals,
    unsigned short* __restrict__ Wq_bf, unsigned short* __restrict__ Wv_bf,
    unsigned short* __restrict__ Wg_bf, unsigned short* __restrict__ vals_bf) {
  const int blk = blockIdx.x;
  if (blk < 256) {
    const int row  = blk * 4 + (threadIdx.x >> 6);
    const int lane = threadIdx.x & 63;
    const float4* p4 = (const float4*)(keys + (size_t)row * D_);
    float4 a = p4[lane];
    float4 b = p4[lane + 64];
    float ss = a.x*a.x + a.y*a.y + a.z*a.z + a.w*a.w
             + b.x*b.x + b.y*b.y + b.z*b.z + b.w*b.w;
#pragma unroll
    for (int off = 32; off > 0; off >>= 1) ss += __shfl_xor(ss, off, 64);
    const float inv = 1.0f / fmaxf(sqrtf(ss), 1e-12f);
    a.x *= inv; a.y *= inv; a.z *= inv; a.w *= inv;
    b.x *= inv; b.y *= inv; b.z *= inv; b.w *= inv;
    float4* o4 = (float4*)(keysN + (size_t)row * D_);
    o4[lane]      = a;
    o4[lane + 64] = b;
    ushort4 ua, ub;
    ua.x=f2bf(a.x); ua.y=f2bf(a.y); ua.z=f2bf(a.z); ua.w=f2bf(a.w);
    ub.x=f2bf(b.x); ub.y=f2bf(b.y); ub.z=f2bf(b.z); ub.w=f2bf(b.w);
    *(ushort4*)(kn_bf + (size_t)row * D_ + 4*lane)       = ua;
    *(ushort4*)(kn_bf + (size_t)row * D_ + 256 + 4*lane) = ub;
  } else if (blk < 512) {
    __shared__ float t[32][33];
    const int g = blk - 256;
    const int bx = g & 15, by = g >> 4;
    const int tx = threadIdx.x & 31, ty = threadIdx.x >> 5;
#pragma unroll
    for (int k = 0; k < 4; k++)
      t[ty + 8*k][tx] = Wq[(size_t)(by*32 + ty + 8*k) * 512 + bx*32 + tx];
    __syncthreads();
#pragma unroll
    for (int k = 0; k < 4; k++)
      WqT[(size_t)(bx*32 + ty + 8*k) * 512 + by*32 + tx] = t[tx][ty + 8*k];
  } else {
    const int cb = blk - 512;
    const float* in;
    unsigned short* out;
    int i;
    if (cb < 128)      { in = Wq;   out = Wq_bf;   i = cb * 256 + threadIdx.x; }
    else if (cb < 256) { in = Wv;   out = Wv_bf;   i = (cb - 128) * 256 + threadIdx.x; }
    else if (cb < 512) { in = Wg;   out = Wg_bf;   i = (cb - 256) * 256 + threadIdx.x; }
    else               { in = vals; out = vals_bf; i = (cb - 512) * 256 + threadIdx.x; }
    const float4 a = ((const float4*)in)[2*i];
    const float4 b = ((const float4*)in)[2*i+1];
    u16x8 o;
    o[0]=f2bf(a.x); o[1]=f2bf(a.y); o[2]=f2bf(a.z); o[3]=f2bf(a.w);
    o[4]=f2bf(b.x); o[5]=f2bf(b.y); o[6]=f2bf(b.z); o[7]=f2bf(b.w);
    *(u16x8*)(out + 8*i) = o;
  }
}

// ---------- pre2: blocks 0..127 = sgemm64 (Kp); 128..383 = qgemm_norm --------
__global__ __launch_bounds__(256) void pre2(
    const float* __restrict__ A, const float* __restrict__ Bm,
    float* __restrict__ C,
    const float* __restrict__ query, const unsigned short* __restrict__ Wqbf,
    unsigned short* __restrict__ qnbf, unsigned short* __restrict__ qbf,
    float* __restrict__ invq) {
  __shared__ __align__(16) char arena[74752];  // 73 KB
  const int tid = threadIdx.x;

  if (blockIdx.x < 128) {
    float (*As)[64] = (float(*)[64])(arena);
    float (*Bs)[64] = (float(*)[64])(arena + 4096);
    const int g = blockIdx.x;
    const int bn = g & 7, bm = g >> 3;
    const int tm = tid >> 4, tn = tid & 15;
    const int r = tid >> 2, k4 = (tid & 3) * 4;
    const float* Ap = A  + (size_t)(bm*64 + r) * 512 + k4;
    const float* Bp = Bm + (size_t)(bn*64 + r) * 512 + k4;
    float acc[4][4];
#pragma unroll
    for (int i = 0; i < 4; i++)
#pragma unroll
      for (int j = 0; j < 4; j++) acc[i][j] = 0.0f;

    for (int k0 = 0; k0 < 512; k0 += 16) {
      const float4 av = *(const float4*)(Ap + k0);
      const float4 bv = *(const float4*)(Bp + k0);
      As[k4+0][r]=av.x; As[k4+1][r]=av.y; As[k4+2][r]=av.z; As[k4+3][r]=av.w;
      Bs[k4+0][r]=bv.x; Bs[k4+1][r]=bv.y; Bs[k4+2][r]=bv.z; Bs[k4+3][r]=bv.w;
      __syncthreads();
#pragma unroll
      for (int k = 0; k < 16; k++) {
        const float4 a = *(const float4*)&As[k][tm*4];
        const float4 b = *(const float4*)&Bs[k][tn*4];
        const float aa[4] = {a.x,a.y,a.z,a.w}, bb[4] = {b.x,b.y,b.z,b.w};
#pragma unroll
        for (int i = 0; i < 4; i++)
#pragma unroll
          for (int j = 0; j < 4; j++) acc[i][j] = fmaf(aa[i], bb[j], acc[i][j]);
      }
      __syncthreads();
    }
#pragma unroll
    for (int i = 0; i < 4; i++) {
      float4 o = make_float4(acc[i][0], acc[i][1], acc[i][2], acc[i][3]);
      *(float4*)(C + (size_t)(bm*64 + tm*4 + i) * 512 + bn*64 + tn*4) = o;
    }
    return;
  }

  unsigned short* AsB = (unsigned short*)(arena);            // [2][64*32]
  unsigned short* BsB = (unsigned short*)(arena + 8192);     // [2][512*32]
  float (*rowss)[64] = (float(*)[64])(arena + 8192 + 65536); // [4][64]
  const int wv = tid >> 6, l = tid & 63;
  const int m0 = (blockIdx.x - 128) * 64;
  const int lane16 = l & 15, lhi = l >> 4;

  f32x4 acc[4][8];
#pragma unroll
  for (int mi = 0; mi < 4; mi++)
#pragma unroll
    for (int nj = 0; nj < 8; nj++)
#pragma unroll
      for (int r = 0; r < 4; r++) acc[mi][nj][r] = 0.0f;

  auto stage = [&](int buf, int t) {
    const int k0 = t * 32;
    {
      const int p = tid;
      const int r = p >> 2, c = p & 3;
      const int q = k0 + 8 * (c ^ ((r >> 1) & 3));
      const float* src = query + (size_t)(m0 + r) * 512 + q;
      const float4 f0 = *(const float4*)src;
      const float4 f1 = *(const float4*)(src + 4);
      u16x8 o;
      o[0]=f2bf(f0.x); o[1]=f2bf(f0.y); o[2]=f2bf(f0.z); o[3]=f2bf(f0.w);
      o[4]=f2bf(f1.x); o[5]=f2bf(f1.y); o[6]=f2bf(f1.z); o[7]=f2bf(f1.w);
      *(u16x8*)&AsB[buf * 2048 + p * 8] = o;
      *(u16x8*)(qbf + (size_t)(m0 + r) * 512 + q) = o;
    }
#pragma unroll
    for (int h = 0; h < 8; ++h) {
      const int p = tid + 256 * h;
      const int r = p >> 2, c = p & 3;
      const int q = k0 + 8 * (c ^ ((r >> 1) & 3));
      GLDS16(Wqbf + (size_t)r * 512 + q, &BsB[buf * 16384 + (4 * h + wv) * 512]);
    }
  };
  auto compute = [&](int buf) {
    const int achunk = lhi ^ ((lane16 >> 1) & 3);
    bf16x8 af[4], bfr[8];
#pragma unroll
    for (int mi = 0; mi < 4; ++mi)
      af[mi] = *(const bf16x8*)&AsB[buf * 2048 + (mi * 16 + lane16) * 32 + achunk * 8];
#pragma unroll
    for (int nj = 0; nj < 8; ++nj)
      bfr[nj] = *(const bf16x8*)&BsB[buf * 16384 + (wv * 128 + nj * 16 + lane16) * 32 + achunk * 8];
#pragma unroll
    for (int mi = 0; mi < 4; ++mi)
#pragma unroll
      for (int nj = 0; nj < 8; ++nj)
        acc[mi][nj] = __builtin_amdgcn_mfma_f32_16x16x32_bf16(af[mi], bfr[nj], acc[mi][nj], 0, 0, 0);
  };

  stage(0, 0);
  __syncthreads();
  for (int t = 0; t < 15; ++t) {
    stage((t + 1) & 1, t + 1);
    compute(t & 1);
    __syncthreads();
  }
  compute(1);

  float ss[4][4];
#pragma unroll
  for (int mi = 0; mi < 4; mi++)
#pragma unroll
    for (int r = 0; r < 4; r++) ss[mi][r] = 0.0f;
#pragma unroll
  for (int mi = 0; mi < 4; mi++)
#pragma unroll
    for (int nj = 0; nj < 8; nj++)
#pragma unroll
      for (int r = 0; r < 4; r++) {
        const float x = acc[mi][nj][r];
        ss[mi][r] = fmaf(x, x, ss[mi][r]);
      }
#pragma unroll
  for (int off = 1; off < 16; off <<= 1)
#pragma unroll
    for (int mi = 0; mi < 4; mi++)
#pragma unroll
      for (int r = 0; r < 4; r++) ss[mi][r] += __shfl_xor(ss[mi][r], off, 64);
  if (lane16 == 0) {
#pragma unroll
    for (int mi = 0; mi < 4; mi++)
#pragma unroll
      for (int r = 0; r < 4; r++) rowss[wv][mi * 16 + lhi * 4 + r] = ss[mi][r];
  }
  __syncthreads();

#pragma unroll
  for (int mi = 0; mi < 4; mi++) {
#pragma unroll
    for (int r = 0; r < 4; r++) {
      const int row = mi * 16 + lhi * 4 + r;
      const float tot = rowss[0][row] + rowss[1][row] + rowss[2][row] + rowss[3][row];
      const float inv = 1.0f / fmaxf(sqrtf(tot), 1e-12f);
      if (wv == 0 && lane16 == 0) invq[m0 + row] = inv;
#pragma unroll
      for (int nj = 0; nj < 8; nj++)
        qnbf[(size_t)(m0 + row) * 512 + wv * 128 + nj * 16 + lane16] =
            f2bf(acc[mi][nj][r] * inv);
    }
  }
}

// ---------- bf16 MFMA NT GEMM, 128x128, bm-fast ------------------------------
// MODE 0 (sim/wv): A=A0bf;        out: bf16 outbf
// MODE 2 (gate):   A=[A0bf | A1]; out: sigmoid(acc+bg)*bf2f(projbf) -> outf (NT)
template<int KTOT, int NOUT, int MODE>
__global__ __launch_bounds__(256) void mfma_nt(
    const unsigned short* __restrict__ A0bf,
    const unsigned short* __restrict__ A1,
    const unsigned short* __restrict__ Bw,
    const float* __restrict__ bg,
    const unsigned short* __restrict__ projbf,
    float* __restrict__ outf,
    unsigned short* __restrict__ outbf) {
  __shared__ __align__(16) unsigned short As[2][128 * 32];
  __shared__ __align__(16) unsigned short Bs[2][128 * 32];
  const int tid = threadIdx.x;
  const int wv = tid >> 6, l = tid & 63;
  const int bm = blockIdx.x, bn = blockIdx.y;   // bm fast -> XCD shares A
  const int wr = wv >> 1, wc = wv & 1;
  const int lane16 = l & 15, lhi = l >> 4;

  f32x4 acc[4][4];
#pragma unroll
  for (int mi = 0; mi < 4; mi++)
#pragma unroll
    for (int nj = 0; nj < 4; nj++)
#pragma unroll
      for (int r = 0; r < 4; r++) acc[mi][nj][r] = 0.0f;

  auto stage = [&](int buf, int t) {
    const int k0 = t * 32;
#pragma unroll
    for (int h = 0; h < 2; ++h) {
      const int p = tid + 256 * h;
      const int r = p >> 2, c = p & 3;
      const int q = k0 + 8 * (c ^ ((r >> 1) & 3));
      const unsigned short* asrc;
      if constexpr (MODE == 2) {
        asrc = (q < 512) ? (A0bf + (size_t)(bm * 128 + r) * 512 + q)
                         : (A1   + (size_t)(bm * 128 + r) * 512 + (q - 512));
      } else {
        asrc = A0bf + (size_t)(bm * 128 + r) * 512 + q;
      }
      GLDS16(asrc, &As[buf][(4 * h + wv) * 512]);
      const unsigned short* bsrc = Bw + (size_t)(bn * 128 + r) * KTOT + q;
      GLDS16(bsrc, &Bs[buf][(4 * h + wv) * 512]);
    }
  };

  auto compute = [&](int buf) {
    const int achunk = lhi ^ ((lane16 >> 1) & 3);
    bf16x8 af[4], bfr[4];
#pragma unroll
    for (int mi = 0; mi < 4; ++mi)
      af[mi] = *(const bf16x8*)&As[buf][(wr * 64 + mi * 16 + lane16) * 32 + achunk * 8];
#pragma unroll
    for (int nj = 0; nj < 4; ++nj)
      bfr[nj] = *(const bf16x8*)&Bs[buf][(wc * 64 + nj * 16 + lane16) * 32 + achunk * 8];
#pragma unroll
    for (int mi = 0; mi < 4; ++mi)
#pragma unroll
      for (int nj = 0; nj < 4; ++nj)
        acc[mi][nj] = __builtin_amdgcn_mfma_f32_16x16x32_bf16(af[mi], bfr[nj], acc[mi][nj], 0, 0, 0);
  };

  const int NT = KTOT / 32;
  stage(0, 0);
  __syncthreads();
  for (int t = 0; t < NT - 1; ++t) {
    stage((t + 1) & 1, t + 1);
    compute(t & 1);
    __syncthreads();
  }
  compute((NT - 1) & 1);

  const int rowb = bm * 128 + wr * 64 + (lhi << 2);
  const int colb = bn * 128 + wc * 64 + lane16;
#pragma unroll
  for (int mi = 0; mi < 4; ++mi) {
#pragma unroll
    for (int nj = 0; nj < 4; ++nj) {
      const int col = colb + nj * 16;
#pragma unroll
      for (int r = 0; r < 4; ++r) {
        const int row = rowb + mi * 16 + r;
        const size_t o = (size_t)row * NOUT + col;
        const float v = acc[mi][nj][r];
        if constexpr (MODE == 2) {
          const float x = v + bg[col];
          const float g = 1.0f / (1.0f + __expf(-x));
          __builtin_nontemporal_store(g * bf2f(projbf[o]), &outf[o]);
        } else {
          outbf[o] = f2bf(v);
        }
      }
    }
  }
}

// ---------- topk: fused coarse sort + fp32 rescore + softmax + gather --------
__global__ __launch_bounds__(256) void topk_rescore_gather(
    const unsigned short* __restrict__ simbf,
    const float* __restrict__ query,
    const float* __restrict__ invq,
    const float* __restrict__ Kp,
    const unsigned short* __restrict__ valsbf,
    unsigned short* __restrict__ retr) {
  const int w = threadIdx.x >> 6, l = threadIdx.x & 63;
  const int b = blockIdx.x * 4 + w;

  const u16x8* sp = (const u16x8*)(simbf + (size_t)b * E_ + 16 * l);
  const u16x8 s0 = sp[0], s1 = sp[1];
  const float4* qp = (const float4*)(query + (size_t)b * D_ + 8 * l);
  const float4 q0 = qp[0], q1 = qp[1];

  float v[16];
  unsigned pk[16];
#pragma unroll
  for (int j = 0; j < 8; j++) {
    const unsigned u0 = (unsigned short)s0[j];
    const unsigned u1 = (unsigned short)s1[j];
    v[j]     = bf2f((unsigned short)u0);
    v[8 + j] = bf2f((unsigned short)u1);
    const unsigned k0 = u0 ^ ((u0 & 0x8000u) ? 0xFFFFu : 0x8000u);
    const unsigned k1 = u1 ^ ((u1 & 0x8000u) ? 0xFFFFu : 0x8000u);
    pk[j]     = (k0 << 16) | (1023u - (unsigned)(l * 16 + j));
    pk[8 + j] = (k1 << 16) | (1023u - (unsigned)(l * 16 + 8 + j));
  }

  unsigned t0 = 0, t1 = 0, t2 = 0, t3 = 0;
#pragma unroll
  for (int j = 0; j < 16; j++) {
    const unsigned x = pk[j];
    const unsigned a = min(t0, x); t0 = max(t0, x);
    const unsigned c = min(t1, a); t1 = max(t1, a);
    const unsigned d = min(t2, c); t2 = max(t2, c);
    t3 = max(t3, d);
  }

#pragma unroll
  for (int off = 1; off < 64; off <<= 1) {
    const unsigned b0 = (unsigned)__shfl_xor((int)t0, off, 64);
    const unsigned b1 = (unsigned)__shfl_xor((int)t1, off, 64);
    const unsigned b2 = (unsigned)__shfl_xor((int)t2, off, 64);
    const unsigned b3 = (unsigned)__shfl_xor((int)t3, off, 64);
    const unsigned c0 = max(t0, b3), c1 = max(t1, b2);
    const unsigned c2 = max(t2, b1), c3 = max(t3, b0);
    const unsigned d0 = max(c0, c2), d2 = min(c0, c2);
    const unsigned d1 = max(c1, c3), d3 = min(c1, c3);
    t0 = max(d0, d1); t1 = min(d0, d1);
    t2 = max(d2, d3); t3 = min(d2, d3);
  }

  const int i0 = 1023 - (int)(t0 & 1023u);
  const int i1 = 1023 - (int)(t1 & 1023u);
  const int i2 = 1023 - (int)(t2 & 1023u);
  const int i3 = 1023 - (int)(t3 & 1023u);
  const unsigned k16 = t3 >> 16;
  const unsigned u4 = (k16 & 0x8000u) ? (k16 ^ 0x8000u) : (~k16 & 0xFFFFu);
  const float thr = bf2f((unsigned short)u4) - 0.008f;

  const float4* kp0 = (const float4*)(Kp + (size_t)i0 * D_ + 8 * l);
  const float4* kp1 = (const float4*)(Kp + (size_t)i1 * D_ + 8 * l);
  const float4* kp2 = (const float4*)(Kp + (size_t)i2 * D_ + 8 * l);
  const float4* kp3 = (const float4*)(Kp + (size_t)i3 * D_ + 8 * l);
  const float4 a0 = kp0[0], c0 = kp0[1];
  const float4 a1 = kp1[0], c1 = kp1[1];
  const float4 a2 = kp2[0], c2 = kp2[1];
  const float4 a3 = kp3[0], c3 = kp3[1];
  float p0 = q0.x*a0.x, p1 = q0.x*a1.x, p2 = q0.x*a2.x, p3 = q0.x*a3.x;
  p0=fmaf(q0.y,a0.y,p0); p1=fmaf(q0.y,a1.y,p1); p2=fmaf(q0.y,a2.y,p2); p3=fmaf(q0.y,a3.y,p3);
  p0=fmaf(q0.z,a0.z,p0); p1=fmaf(q0.z,a1.z,p1); p2=fmaf(q0.z,a2.z,p2); p3=fmaf(q0.z,a3.z,p3);
  p0=fmaf(q0.w,a0.w,p0); p1=fmaf(q0.w,a1.w,p1); p2=fmaf(q0.w,a2.w,p2); p3=fmaf(q0.w,a3.w,p3);
  p0=fmaf(q1.x,c0.x,p0); p1=fmaf(q1.x,c1.x,p1); p2=fmaf(q1.x,c2.x,p2); p3=fmaf(q1.x,c3.x,p3);
  p0=fmaf(q1.y,c0.y,p0); p1=fmaf(q1.y,c1.y,p1); p2=fmaf(q1.y,c2.y,p2); p3=fmaf(q1.y,c3.y,p3);
  p0=fmaf(q1.z,c0.z,p0); p1=fmaf(q1.z,c1.z,p1); p2=fmaf(q1.z,c2.z,p2); p3=fmaf(q1.z,c3.z,p3);
  p0=fmaf(q1.w,c0.w,p0); p1=fmaf(q1.w,c1.w,p1); p2=fmaf(q1.w,c2.w,p2); p3=fmaf(q1.w,c3.w,p3);
#pragma unroll
  for (int off = 32; off > 0; off >>= 1) {
    p0 += __shfl_xor(p0, off, 64);
    p1 += __shfl_xor(p1, off, 64);
    p2 += __shfl_xor(p2, off, 64);
    p3 += __shfl_xor(p3, off, 64);
  }

  const float NEG = -3.402823466e38f;
  float rv0 = NEG, rv1 = NEG, rv2 = NEG, rv3 = NEG;
  int   ri0 = 0x7fffffff, ri1 = 0x7fffffff, ri2 = 0x7fffffff, ri3 = 0x7fffffff;
  auto ins = [&](float nv, int ni) {
    if (nv > rv0 || (nv == rv0 && ni < ri0)) {
      rv3 = rv2; ri3 = ri2; rv2 = rv1; ri2 = ri1; rv1 = rv0; ri1 = ri0; rv0 = nv; ri0 = ni;
    } else if (nv > rv1 || (nv == rv1 && ni < ri1)) {
      rv3 = rv2; ri3 = ri2; rv2 = rv1; ri2 = ri1; rv1 = nv; ri1 = ni;
    } else if (nv > rv2 || (nv == rv2 && ni < ri2)) {
      rv3 = rv2; ri3 = ri2; rv2 = nv; ri2 = ni;
    } else if (nv > rv3 || (nv == rv3 && ni < ri3)) {
      rv3 = nv; ri3 = ni;
    }
  };
  ins(p0, i0); ins(p1, i1); ins(p2, i2); ins(p3, i3);

  auto score = [&](int idx) -> float {
    const float4* kp = (const float4*)(Kp + (size_t)idx * D_ + 8 * l);
    const float4 k0 = kp[0], k1 = kp[1];
    float p = q0.x * k0.x;
    p = fmaf(q0.y, k0.y, p); p = fmaf(q0.z, k0.z, p); p = fmaf(q0.w, k0.w, p);
    p = fmaf(q1.x, k1.x, p); p = fmaf(q1.y, k1.y, p);
    p = fmaf(q1.z, k1.z, p); p = fmaf(q1.w, k1.w, p);
#pragma unroll
    for (int off = 32; off > 0; off >>= 1) p += __shfl_xor(p, off, 64);
    return p;
  };
#pragma unroll
  for (int s = 0; s < 16; s++) {
    const int idx = l * 16 + s;
    const bool pred = (v[s] >= thr) && idx != i0 && idx != i1 && idx != i2 && idx != i3;
    unsigned long long m = __ballot(pred);
    while (m) {
      const int ln = __builtin_ctzll(m);
      m &= m - 1;
      const int ci = ln * 16 + s;
      ins(score(ci), ci);
    }
  }

  const float iq = invq[b];
  const float f0 = rv0 * iq, f1 = rv1 * iq, f2 = rv2 * iq, f3 = rv3 * iq;
  const float mx = 5.0f * f0;
  const float e0 = expf(5.0f * f0 - mx), e1 = expf(5.0f * f1 - mx);
  const float e2 = expf(5.0f * f2 - mx), e3 = expf(5.0f * f3 - mx);
  const float wi = 1.0f / (e0 + e1 + e2 + e3);
  const float w0 = e0 * wi, w1 = e1 * wi, w2 = e2 * wi, w3 = e3 * wi;

  const u16x8 g0 = *(const u16x8*)(valsbf + (size_t)ri0 * D_ + 8 * l);
  const u16x8 g1 = *(const u16x8*)(valsbf + (size_t)ri1 * D_ + 8 * l);
  const u16x8 g2 = *(const u16x8*)(valsbf + (size_t)ri2 * D_ + 8 * l);
  const u16x8 g3 = *(const u16x8*)(valsbf + (size_t)ri3 * D_ + 8 * l);
  u16x8 o;
#pragma unroll
  for (int j = 0; j < 8; j++) {
    o[j] = f2bf(w0 * bf2f((unsigned short)g0[j]) + w1 * bf2f((unsigned short)g1[j]) +
                w2 * bf2f((unsigned short)g2[j]) + w3 * bf2f((unsigned short)g3[j]));
  }
  *(u16x8*)(retr + (size_t)b * D_ + 8 * l) = o;
}

extern "C" void kernel_launch(void* const* d_in, const int* in_sizes, int n_in,
                              void* d_out, int out_size, void* d_ws, size_t ws_size,
                              hipStream_t stream) {
  (void)in_sizes; (void)n_in; (void)out_size; (void)ws_size;
  const float* query = (const float*)d_in[0];
  const float* keys  = (const float*)d_in[1];
  const float* vals  = (const float*)d_in[2];
  const float* Wq    = (const float*)d_in[3];
  const float* Wv    = (const float*)d_in[4];
  const float* Wg    = (const float*)d_in[5];
  const float* bg    = (const float*)d_in[6];
  float* out = (float*)d_out;

  char* ws = (char*)d_ws;
  const size_t M = 1u << 20;
  unsigned short* sim_bf   = (unsigned short*)(ws);          // [0,32M)
  unsigned short* qn_bf    = (unsigned short*)(ws + 32*M);   // [32M,48M)
  unsigned short* retr_bf  = (unsigned short*)(ws + 32*M);   // overlay after sim
  unsigned short* proj_bf  = (unsigned short*)(ws + 48*M);   // [48M,64M)
  float*          keysN    = (float*)(ws + 64*M);            // 2 MB
  unsigned short* kn_bf    = (unsigned short*)(ws + 66*M);   // 1 MB
  float*          WqT      = (float*)(ws + 67*M);            // 1 MB
  float*          Kp       = (float*)(ws + 68*M);            // 2 MB
  unsigned short* Wq_bf    = (unsigned short*)(ws + 70*M);   // 0.5 MB
  unsigned short* Wv_bf    = (unsigned short*)(ws + 70*M + 512*1024u);
  unsigned short* Wg_bf    = (unsigned short*)(ws + 71*M);   // 1 MB
  float*          invq     = (float*)(ws + 72*M);            // 64 KB
  unsigned short* query_bf = (unsigned short*)(ws + 74*M);   // [74M,90M)
  unsigned short* vals_bf  = (unsigned short*)(ws + 90*M);   // 1 MB

  // fused prep: l2norm_keys + WqT transpose + bf16 conversions
  prep<<<1280, 256, 0, stream>>>(keys, keysN, kn_bf, Wq, WqT, Wv, Wg, vals,
                                 Wq_bf, Wv_bf, Wg_bf, vals_bf);

  // fused: Kp GEMM (blocks 0..127) || qgemm_norm (blocks 128..383)
  pre2<<<384, 256, 0, stream>>>(keysN, WqT, Kp,
                                query, Wq_bf, qn_bf, query_bf, invq);

  // coarse sim (bf16 out): [B,E]; bm fast
  mfma_nt<512, 1024, 0><<<dim3(B_ / 128, E_ / 128), 256, 0, stream>>>(
      qn_bf, nullptr, kn_bf, nullptr, nullptr, nullptr, sim_bf);

  topk_rescore_gather<<<B_ / 4, 256, 0, stream>>>(sim_bf, query, invq, Kp,
                                                  vals_bf, retr_bf);

  // proj = retrieved @ Wv^T; bm fast
  mfma_nt<512, 512, 0><<<dim3(B_ / 128, D_ / 128), 256, 0, stream>>>(
      retr_bf, nullptr, Wv_bf, nullptr, nullptr, nullptr, proj_bf);

  // out = sigmoid([query|proj] @ Wg^T + bg) * proj; bm fast; NT out store
  mfma_nt<1024, 512, 2><<<dim3(B_ / 128, D_ / 128), 256, 0, stream>>>(
      query_bf, proj_bf, Wg_bf, bg, proj_bf, out, nullptr);
}